// Round 8
// baseline (135.966 us; speedup 1.0000x reference)
//
#include <hip/hip_runtime.h>
#include <cstddef>

// RetNetAttention round 8: group-of-4-chunk middle section (state carried in MFMA
// accumulators, GL/GS group scan), GEMMs and cast unchanged from R7.
#define NB 2
#define NL 4096
#define ND 1024
#define NH 16
#define DKH 64
#define CK 64
#define NCH (NL / CK)     // 64 chunks
#define NG 16             // groups per bh (4 chunks each)
#define NM (NB * NL)
#define KD 1024

typedef __attribute__((ext_vector_type(8))) short bf16x8;
typedef __attribute__((ext_vector_type(4))) float f32x4;

__device__ __forceinline__ float dsigmoid(float x) { return 1.0f / (1.0f + __expf(-x)); }
__device__ __forceinline__ float bf2f(unsigned short u) { return __uint_as_float((unsigned)u << 16); }
__device__ __forceinline__ unsigned short f2bf(float f) {
    unsigned u = __float_as_uint(f);
    u = (u + 0x7fffu + ((u >> 16) & 1u)) >> 16;
    return (unsigned short)u;
}
// element index into [R][64]-ushort tile, XOR-swizzled at 8-elem (16B) granularity
__device__ __forceinline__ int swz(int row, int col) { return row * 64 + (col ^ ((row & 7) << 3)); }

__device__ __forceinline__ void gload16(const void* g, void* l) {
    __builtin_amdgcn_global_load_lds(
        (const __attribute__((address_space(1))) unsigned int*)g,
        (__attribute__((address_space(3))) unsigned int*)l, 16, 0, 0);
}

// ================= fused fp32 -> bf16 casts =================
__global__ __launch_bounds__(256)
void k_cast_all(const float* __restrict__ x, const float* __restrict__ Wq,
                const float* __restrict__ Wo, unsigned short* __restrict__ xb,
                unsigned short* __restrict__ Wqb, unsigned short* __restrict__ Wob)
{
    const int N1 = NB * NL * ND / 4;
    const int N2 = 3 * ND * ND / 4;
    const int N3 = ND * ND / 4;
    const int total = N1 + N2 + N3;
    int i = blockIdx.x * 256 + threadIdx.x;
    const int stride = gridDim.x * 256;
    for (; i < total; i += stride) {
        const float4* src;
        ushort4* dst;
        int j;
        if (i < N1)            { src = (const float4*)x;  dst = (ushort4*)xb;  j = i; }
        else if (i < N1 + N2)  { src = (const float4*)Wq; dst = (ushort4*)Wqb; j = i - N1; }
        else                   { src = (const float4*)Wo; dst = (ushort4*)Wob; j = i - N1 - N2; }
        float4 v = src[j];
        ushort4 o;
        o.x = f2bf(v.x); o.y = f2bf(v.y); o.z = f2bf(v.z); o.w = f2bf(v.w);
        dst[j] = o;
    }
}

// ====== bf16 MFMA GEMM (NT), 128x128 tile, BK=64, swizzled LDS reads (proven 899 TF) ======
__global__ __launch_bounds__(256)
void k_gemm_qkv_bf16(const unsigned short* __restrict__ A, const unsigned short* __restrict__ Bm,
                     unsigned short* __restrict__ Qb, unsigned short* __restrict__ Kb,
                     unsigned short* __restrict__ Vb)
{
    __shared__ short As[128 * 64];
    __shared__ short Bs[128 * 64];
    const int tid = threadIdx.x;
    const int w = tid >> 6, lane = tid & 63;
    const int wr = w >> 1, wc = w & 1;
    const int lr = lane & 15, lk = lane >> 4;

    const int nbx = gridDim.x;
    const int nwg = nbx * gridDim.y;
    const int bid = blockIdx.y * nbx + blockIdx.x;
    const int sb  = (bid & 7) * (nwg >> 3) + (bid >> 3);
    const int row0 = (sb / nbx) * 128, col0 = (sb % nbx) * 128;

    const int srow = tid >> 3;
    const int schk = (tid & 7) ^ (srow & 7);
    const unsigned short* gA = A + (size_t)(row0 + srow) * KD + schk * 8;
    const unsigned short* gB = Bm + (size_t)(col0 + srow) * KD + schk * 8;
    short* lA = As + (w * 8) * 64;
    short* lB = Bs + (w * 8) * 64;

    f32x4 acc[4][4];
#pragma unroll
    for (int m = 0; m < 4; ++m)
#pragma unroll
        for (int n = 0; n < 4; ++n) acc[m][n] = (f32x4){0.f, 0.f, 0.f, 0.f};

    int arow[4], brow[4];
#pragma unroll
    for (int m = 0; m < 4; ++m) arow[m] = (wr * 64 + m * 16 + lr) * 64;
#pragma unroll
    for (int n = 0; n < 4; ++n) brow[n] = (wc * 64 + n * 16 + lr) * 64;
    const int xr = lr & 7;
    const int coff0 = ((0 * 4 + lk) ^ xr) * 8;
    const int coff1 = ((1 * 4 + lk) ^ xr) * 8;

    for (int k0 = 0; k0 < KD; k0 += 64) {
#pragma unroll
        for (int i = 0; i < 4; ++i) gload16(gA + (size_t)(i * 32) * KD + k0, lA + i * 2048);
#pragma unroll
        for (int i = 0; i < 4; ++i) gload16(gB + (size_t)(i * 32) * KD + k0, lB + i * 2048);
        __syncthreads();
#pragma unroll
        for (int kk = 0; kk < 2; ++kk) {
            const int co = kk ? coff1 : coff0;
            bf16x8 a[4], b[4];
#pragma unroll
            for (int m = 0; m < 4; ++m) a[m] = *(const bf16x8*)(As + arow[m] + co);
#pragma unroll
            for (int n = 0; n < 4; ++n) b[n] = *(const bf16x8*)(Bs + brow[n] + co);
#pragma unroll
            for (int m = 0; m < 4; ++m)
#pragma unroll
                for (int n = 0; n < 4; ++n)
                    acc[m][n] = __builtin_amdgcn_mfma_f32_16x16x32_bf16(a[m], b[n], acc[m][n], 0, 0, 0);
        }
        __syncthreads();
    }

#pragma unroll
    for (int m = 0; m < 4; ++m) {
        const int mrow0 = row0 + wr * 64 + m * 16 + lk * 4;
#pragma unroll
        for (int n = 0; n < 4; ++n) {
            const int gcol = col0 + wc * 64 + n * 16 + lr;
            const int three = gcol >> 10;
            const int h = (gcol >> 6) & (NH - 1);
            const int d = gcol & (DKH - 1);
            unsigned short* dst = (three == 0) ? Qb : ((three == 1) ? Kb : Vb);
#pragma unroll
            for (int j = 0; j < 4; ++j) {
                const int mr = mrow0 + j;
                const int b = mr >> 12;
                const int t = mr & (NL - 1);
                dst[(((size_t)b * NH + h) * NL + t) * DKH + d] = f2bf(acc[m][n][j]);
            }
        }
    }
}

__global__ __launch_bounds__(256)
void k_gemm_out_bf16(const unsigned short* __restrict__ A, const unsigned short* __restrict__ Bm,
                     float* __restrict__ C)
{
    __shared__ short As[128 * 64];
    __shared__ short Bs[128 * 64];
    const int tid = threadIdx.x;
    const int w = tid >> 6, lane = tid & 63;
    const int wr = w >> 1, wc = w & 1;
    const int lr = lane & 15, lk = lane >> 4;

    const int nbx = gridDim.x;
    const int nwg = nbx * gridDim.y;
    const int bid = blockIdx.y * nbx + blockIdx.x;
    const int sb  = (bid & 7) * (nwg >> 3) + (bid >> 3);
    const int row0 = (sb / nbx) * 128, col0 = (sb % nbx) * 128;

    const int srow = tid >> 3;
    const int schk = (tid & 7) ^ (srow & 7);
    const unsigned short* gA = A + (size_t)(row0 + srow) * KD + schk * 8;
    const unsigned short* gB = Bm + (size_t)(col0 + srow) * KD + schk * 8;
    short* lA = As + (w * 8) * 64;
    short* lB = Bs + (w * 8) * 64;

    f32x4 acc[4][4];
#pragma unroll
    for (int m = 0; m < 4; ++m)
#pragma unroll
        for (int n = 0; n < 4; ++n) acc[m][n] = (f32x4){0.f, 0.f, 0.f, 0.f};

    int arow[4], brow[4];
#pragma unroll
    for (int m = 0; m < 4; ++m) arow[m] = (wr * 64 + m * 16 + lr) * 64;
#pragma unroll
    for (int n = 0; n < 4; ++n) brow[n] = (wc * 64 + n * 16 + lr) * 64;
    const int xr = lr & 7;
    const int coff0 = ((0 * 4 + lk) ^ xr) * 8;
    const int coff1 = ((1 * 4 + lk) ^ xr) * 8;

    for (int k0 = 0; k0 < KD; k0 += 64) {
#pragma unroll
        for (int i = 0; i < 4; ++i) gload16(gA + (size_t)(i * 32) * KD + k0, lA + i * 2048);
#pragma unroll
        for (int i = 0; i < 4; ++i) gload16(gB + (size_t)(i * 32) * KD + k0, lB + i * 2048);
        __syncthreads();
#pragma unroll
        for (int kk = 0; kk < 2; ++kk) {
            const int co = kk ? coff1 : coff0;
            bf16x8 a[4], b[4];
#pragma unroll
            for (int m = 0; m < 4; ++m) a[m] = *(const bf16x8*)(As + arow[m] + co);
#pragma unroll
            for (int n = 0; n < 4; ++n) b[n] = *(const bf16x8*)(Bs + brow[n] + co);
#pragma unroll
            for (int m = 0; m < 4; ++m)
#pragma unroll
                for (int n = 0; n < 4; ++n)
                    acc[m][n] = __builtin_amdgcn_mfma_f32_16x16x32_bf16(a[m], b[n], acc[m][n], 0, 0, 0);
        }
        __syncthreads();
    }

#pragma unroll
    for (int m = 0; m < 4; ++m) {
        const int mrow0 = row0 + wr * 64 + m * 16 + lk * 4;
#pragma unroll
        for (int n = 0; n < 4; ++n) {
            const int gcol = col0 + wc * 64 + n * 16 + lr;
#pragma unroll
            for (int j = 0; j < 4; ++j)
                C[(size_t)(mrow0 + j) * ND + gcol] = acc[m][n][j];
        }
    }
}

// ====== group state: GL[bh][g][d][e] = sum_{u=0..255} g^{255-u} v_u[d] ln(k_u)[e] ======
// State kept in MFMA accumulators across the 4 chunks (scale by g^64 between chunks).
__global__ __launch_bounds__(256)
void k_group_state(const unsigned short* __restrict__ Kb, const unsigned short* __restrict__ Vb,
                   const float* __restrict__ lg, unsigned short* __restrict__ GL)
{
    __shared__ unsigned short Kt[64 * 64];   // weighted LN'd K^T [e][s]
    __shared__ unsigned short Vt[64 * 64];   // raw V^T [d][s]
    __shared__ float red[64][8];
    const int blk = blockIdx.x;              // bh*16 + g
    const int g   = blk & (NG - 1);
    const int bh  = blk >> 4;
    const int h   = bh & (NH - 1);
    const float gamma = dsigmoid(lg[h]);
    const float l2g  = log2f(gamma);
    const float dc64 = exp2f(64.0f * l2g);
    const int tid = threadIdx.x;
    const int r  = tid & 63;
    const int w4 = tid >> 6;
    const int c0 = w4 * 8;
    const int w = tid >> 6, lane = tid & 63;
    const int wr = w >> 1, wc = w & 1;
    const int lr = lane & 15, lk = lane >> 4;

    f32x4 acc[2][2];
#pragma unroll
    for (int m = 0; m < 2; ++m)
#pragma unroll
        for (int n = 0; n < 2; ++n) acc[m][n] = (f32x4){0.f, 0.f, 0.f, 0.f};

    bf16x8 k8[2][2], v8[2][2];
    {
        const unsigned short* Kc = Kb + ((size_t)bh * NL + (g * 4) * CK) * DKH;
        const unsigned short* Vc = Vb + ((size_t)bh * NL + (g * 4) * CK) * DKH;
        k8[0][0] = *(const bf16x8*)(Kc + (size_t)r * DKH + c0);
        k8[0][1] = *(const bf16x8*)(Kc + (size_t)r * DKH + c0 + 32);
        v8[0][0] = *(const bf16x8*)(Vc + (size_t)r * DKH + c0);
        v8[0][1] = *(const bf16x8*)(Vc + (size_t)r * DKH + c0 + 32);
    }

#pragma unroll
    for (int ci = 0; ci < 4; ++ci) {
        const int cb = ci & 1;
        float sum = 0.f, sq = 0.f;
#pragma unroll
        for (int j = 0; j < 8; ++j) {
            float xa = bf2f((unsigned short)k8[cb][0][j]); sum += xa; sq += xa * xa;
            float xb = bf2f((unsigned short)k8[cb][1][j]); sum += xb; sq += xb * xb;
        }
        red[r][w4] = sum; red[r][w4 + 4] = sq;
        __syncthreads();   // also guarantees prev chunk's MFMA LDS reads are done
        float sm = red[r][0] + red[r][1] + red[r][2] + red[r][3];
        float qq = red[r][4] + red[r][5] + red[r][6] + red[r][7];
        float mu = sm * (1.0f / 64.0f);
        float rstd = rsqrtf(qq * (1.0f / 64.0f) - mu * mu + 1e-5f);
        float wgt = exp2f((float)(CK - 1 - r) * l2g);
#pragma unroll
        for (int j = 0; j < 8; ++j) {
            Kt[swz(c0 + j, r)]      = f2bf((bf2f((unsigned short)k8[cb][0][j]) - mu) * rstd * wgt);
            Kt[swz(c0 + 32 + j, r)] = f2bf((bf2f((unsigned short)k8[cb][1][j]) - mu) * rstd * wgt);
            Vt[swz(c0 + j, r)]      = (unsigned short)v8[cb][0][j];
            Vt[swz(c0 + 32 + j, r)] = (unsigned short)v8[cb][1][j];
        }
        if (ci < 3) {   // prefetch next chunk
            const int c = g * 4 + ci + 1;
            const unsigned short* Kc = Kb + ((size_t)bh * NL + c * CK) * DKH;
            const unsigned short* Vc = Vb + ((size_t)bh * NL + c * CK) * DKH;
            k8[cb ^ 1][0] = *(const bf16x8*)(Kc + (size_t)r * DKH + c0);
            k8[cb ^ 1][1] = *(const bf16x8*)(Kc + (size_t)r * DKH + c0 + 32);
            v8[cb ^ 1][0] = *(const bf16x8*)(Vc + (size_t)r * DKH + c0);
            v8[cb ^ 1][1] = *(const bf16x8*)(Vc + (size_t)r * DKH + c0 + 32);
        }
        __syncthreads();
        if (ci > 0) {
#pragma unroll
            for (int m = 0; m < 2; ++m)
#pragma unroll
                for (int n = 0; n < 2; ++n) acc[m][n] = acc[m][n] * dc64;
        }
#pragma unroll
        for (int kk = 0; kk < 2; ++kk) {
            const int so = kk * 32 + lk * 8;
            bf16x8 a[2], b[2];
#pragma unroll
            for (int m = 0; m < 2; ++m) a[m] = *(const bf16x8*)&Vt[swz(wr * 32 + m * 16 + lr, so)];
#pragma unroll
            for (int n = 0; n < 2; ++n) b[n] = *(const bf16x8*)&Kt[swz(wc * 32 + n * 16 + lr, so)];
#pragma unroll
            for (int m = 0; m < 2; ++m)
#pragma unroll
                for (int n = 0; n < 2; ++n)
                    acc[m][n] = __builtin_amdgcn_mfma_f32_16x16x32_bf16(a[m], b[n], acc[m][n], 0, 0, 0);
        }
    }

    unsigned short* out = GL + (size_t)blk * (DKH * DKH);
#pragma unroll
    for (int m = 0; m < 2; ++m)
#pragma unroll
        for (int n = 0; n < 2; ++n)
#pragma unroll
            for (int j = 0; j < 4; ++j) {
                int d = wr * 32 + m * 16 + lk * 4 + j;
                int e = wc * 32 + n * 16 + lr;
                out[d * DKH + e] = f2bf(acc[m][n][j]);
            }
}

// ====== scan over 16 groups: GS[g] = state BEFORE group g ======
__global__ __launch_bounds__(64)
void k_scan16(const unsigned short* __restrict__ GL, const float* __restrict__ lg,
              unsigned short* __restrict__ GS)
{
    const int bh = blockIdx.x;                 // 0..31
    const int qt = blockIdx.y;                 // 0..15
    const int h  = bh & (NH - 1);
    const float gamma = dsigmoid(lg[h]);
    const float dc = exp2f(256.0f * log2f(gamma));
    const size_t base = (size_t)bh * NG * (DKH * DKH) + qt * 256 + threadIdx.x * 4;
    float s0 = 0.f, s1 = 0.f, s2 = 0.f, s3 = 0.f;
    for (int g = 0; g < NG; ++g) {
        const size_t off = base + (size_t)g * (DKH * DKH);
        ushort4 l = *(const ushort4*)(GL + off);
        ushort4 o;
        o.x = f2bf(s0); o.y = f2bf(s1); o.z = f2bf(s2); o.w = f2bf(s3);
        *(ushort4*)(GS + off) = o;
        s0 = s0 * dc + bf2f(l.x); s1 = s1 * dc + bf2f(l.y);
        s2 = s2 * dc + bf2f(l.z); s3 = s3 * dc + bf2f(l.w);
    }
}

// ====== chunk output, 4 chunks/block, state in accumulators ======
__global__ __launch_bounds__(256)
void k_chunk_out4(const unsigned short* __restrict__ Qb, const unsigned short* __restrict__ Kb,
                  const unsigned short* __restrict__ Vb, const unsigned short* __restrict__ GS,
                  const float* __restrict__ lg, unsigned short* __restrict__ Y)
{
    __shared__ unsigned short Qs[64 * 64];    // Q[t][e]
    __shared__ unsigned short Ks[64 * 64];    // ln(K)[s][e]
    __shared__ unsigned short Kwt[64 * 64];   // g^{63-s} ln(K)^T [e][s]
    __shared__ unsigned short Vt[64 * 64];    // V^T [d][s]
    __shared__ unsigned short Ps[64 * 64];    // P / Y staging
    __shared__ unsigned short Sbf[64 * 64];   // S at chunk start [d][e]
    __shared__ float red[64][8];
    const int blk = blockIdx.x;               // bh*16 + g
    const int g   = blk & (NG - 1);
    const int bh  = blk >> 4;
    const int h   = bh & (NH - 1);
    const int b   = bh >> 4;
    const float gamma = dsigmoid(lg[h]);
    const float l2g  = log2f(gamma);
    const float dc64 = exp2f(64.0f * l2g);
    const int tid = threadIdx.x;
    const int r  = tid & 63;
    const int w4 = tid >> 6;
    const int c0 = w4 * 8;
    const int w = tid >> 6, lane = tid & 63;
    const int wr = w >> 1, wc = w & 1;
    const int lr = lane & 15, lk = lane >> 4;

    // ---- init S from GS (stage through Sbf) ----
    {
        const unsigned short* Gp = GS + (size_t)blk * (DKH * DKH);
        *(bf16x8*)&Sbf[swz(r, c0)]      = *(const bf16x8*)(Gp + (size_t)r * DKH + c0);
        *(bf16x8*)&Sbf[swz(r, c0 + 32)] = *(const bf16x8*)(Gp + (size_t)r * DKH + c0 + 32);
    }
    __syncthreads();
    f32x4 S_acc[2][2];
#pragma unroll
    for (int m = 0; m < 2; ++m)
#pragma unroll
        for (int n = 0; n < 2; ++n)
#pragma unroll
            for (int j = 0; j < 4; ++j)
                S_acc[m][n][j] = bf2f(Sbf[swz(wr * 32 + m * 16 + lk * 4 + j, wc * 32 + n * 16 + lr)]);

    // ---- preload chunk 0 ----
    bf16x8 q8[2][2], k8[2][2], v8[2][2];
    {
        const size_t rowb = ((size_t)bh * NL + (g * 4) * CK + r) * DKH;
        q8[0][0] = *(const bf16x8*)(Qb + rowb + c0);
        q8[0][1] = *(const bf16x8*)(Qb + rowb + c0 + 32);
        k8[0][0] = *(const bf16x8*)(Kb + rowb + c0);
        k8[0][1] = *(const bf16x8*)(Kb + rowb + c0 + 32);
        v8[0][0] = *(const bf16x8*)(Vb + rowb + c0);
        v8[0][1] = *(const bf16x8*)(Vb + rowb + c0 + 32);
    }

#pragma unroll
    for (int ci = 0; ci < 4; ++ci) {
        const int cb = ci & 1;
        const int c  = g * 4 + ci;
        // K stats
        float sum = 0.f, sq = 0.f;
#pragma unroll
        for (int j = 0; j < 8; ++j) {
            float xa = bf2f((unsigned short)k8[cb][0][j]); sum += xa; sq += xa * xa;
            float xb = bf2f((unsigned short)k8[cb][1][j]); sum += xb; sq += xb * xb;
        }
        red[r][w4] = sum; red[r][w4 + 4] = sq;
        __syncthreads();                          // B1: prev-iter LDS reads all done
        float sm = red[r][0] + red[r][1] + red[r][2] + red[r][3];
        float qq = red[r][4] + red[r][5] + red[r][6] + red[r][7];
        float mu = sm * (1.0f / 64.0f);
        float rstd = rsqrtf(qq * (1.0f / 64.0f) - mu * mu + 1e-5f);
        float wgt = exp2f((float)(CK - 1 - r) * l2g);
        *(bf16x8*)&Qs[swz(r, c0)]      = q8[cb][0];
        *(bf16x8*)&Qs[swz(r, c0 + 32)] = q8[cb][1];
#pragma unroll
        for (int j = 0; j < 8; ++j) {
            float ka = (bf2f((unsigned short)k8[cb][0][j]) - mu) * rstd;
            float kb_ = (bf2f((unsigned short)k8[cb][1][j]) - mu) * rstd;
            Ks[swz(r, c0 + j)]       = f2bf(ka);
            Ks[swz(r, c0 + 32 + j)]  = f2bf(kb_);
            Kwt[swz(c0 + j, r)]      = f2bf(ka * wgt);
            Kwt[swz(c0 + 32 + j, r)] = f2bf(kb_ * wgt);
            Vt[swz(c0 + j, r)]       = (unsigned short)v8[cb][0][j];
            Vt[swz(c0 + 32 + j, r)]  = (unsigned short)v8[cb][1][j];
        }
        // Sbf <- S at chunk start (pre-update)
#pragma unroll
        for (int m = 0; m < 2; ++m)
#pragma unroll
            for (int n = 0; n < 2; ++n)
#pragma unroll
                for (int j = 0; j < 4; ++j)
                    Sbf[swz(wr * 32 + m * 16 + lk * 4 + j, wc * 32 + n * 16 + lr)] =
                        f2bf(S_acc[m][n][j]);
        __syncthreads();                          // B2

        // phase A: P = Q K^T with causal decay
        f32x4 accp[2][2];
#pragma unroll
        for (int m = 0; m < 2; ++m)
#pragma unroll
            for (int n = 0; n < 2; ++n) accp[m][n] = (f32x4){0.f, 0.f, 0.f, 0.f};
#pragma unroll
        for (int kk = 0; kk < 2; ++kk) {
            const int eo = kk * 32 + lk * 8;
            bf16x8 a[2], bfr[2];
#pragma unroll
            for (int m = 0; m < 2; ++m) a[m]   = *(const bf16x8*)&Qs[swz(wr * 32 + m * 16 + lr, eo)];
#pragma unroll
            for (int n = 0; n < 2; ++n) bfr[n] = *(const bf16x8*)&Ks[swz(wc * 32 + n * 16 + lr, eo)];
#pragma unroll
            for (int m = 0; m < 2; ++m)
#pragma unroll
                for (int n = 0; n < 2; ++n)
                    accp[m][n] = __builtin_amdgcn_mfma_f32_16x16x32_bf16(a[m], bfr[n], accp[m][n], 0, 0, 0);
        }
#pragma unroll
        for (int m = 0; m < 2; ++m)
#pragma unroll
            for (int n = 0; n < 2; ++n)
#pragma unroll
                for (int j = 0; j < 4; ++j) {
                    int t = wr * 32 + m * 16 + lk * 4 + j;
                    int s = wc * 32 + n * 16 + lr;
                    int dt = t - s;
                    float v = (dt >= 0) ? accp[m][n][j] * exp2f((float)dt * l2g) : 0.0f;
                    Ps[swz(t, s)] = f2bf(v);
                }
        // prefetch next chunk (hidden under phase B)
        if (ci < 3) {
            const size_t rowb = ((size_t)bh * NL + (c + 1) * CK + r) * DKH;
            q8[cb ^ 1][0] = *(const bf16x8*)(Qb + rowb + c0);
            q8[cb ^ 1][1] = *(const bf16x8*)(Qb + rowb + c0 + 32);
            k8[cb ^ 1][0] = *(const bf16x8*)(Kb + rowb + c0);
            k8[cb ^ 1][1] = *(const bf16x8*)(Kb + rowb + c0 + 32);
            v8[cb ^ 1][0] = *(const bf16x8*)(Vb + rowb + c0);
            v8[cb ^ 1][1] = *(const bf16x8*)(Vb + rowb + c0 + 32);
        }
        __syncthreads();                          // B3

        // phase B: Y = P V + g^{t+1} Q S^T ; S <- g^64 S + V^T Kwt
#pragma unroll
        for (int m = 0; m < 2; ++m)
#pragma unroll
            for (int n = 0; n < 2; ++n) S_acc[m][n] = S_acc[m][n] * dc64;
        f32x4 accy[2][2], accz[2][2];
#pragma unroll
        for (int m = 0; m < 2; ++m)
#pragma unroll
            for (int n = 0; n < 2; ++n) {
                accy[m][n] = (f32x4){0.f, 0.f, 0.f, 0.f};
                accz[m][n] = (f32x4){0.f, 0.f, 0.f, 0.f};
            }
#pragma unroll
        for (int kk = 0; kk < 2; ++kk) {
            const int so = kk * 32 + lk * 8;
            bf16x8 pa[2], qa[2], va[2], vb[2], sb[2], kb2[2];
#pragma unroll
            for (int m = 0; m < 2; ++m) {
                pa[m] = *(const bf16x8*)&Ps[swz(wr * 32 + m * 16 + lr, so)];
                qa[m] = *(const bf16x8*)&Qs[swz(wr * 32 + m * 16 + lr, so)];
                va[m] = *(const bf16x8*)&Vt[swz(wr * 32 + m * 16 + lr, so)];
            }
#pragma unroll
            for (int n = 0; n < 2; ++n) {
                vb[n]  = *(const bf16x8*)&Vt[swz(wc * 32 + n * 16 + lr, so)];
                sb[n]  = *(const bf16x8*)&Sbf[swz(wc * 32 + n * 16 + lr, so)];
                kb2[n] = *(const bf16x8*)&Kwt[swz(wc * 32 + n * 16 + lr, so)];
            }
#pragma unroll
            for (int m = 0; m < 2; ++m)
#pragma unroll
                for (int n = 0; n < 2; ++n) {
                    accy[m][n]  = __builtin_amdgcn_mfma_f32_16x16x32_bf16(pa[m], vb[n],  accy[m][n], 0, 0, 0);
                    accz[m][n]  = __builtin_amdgcn_mfma_f32_16x16x32_bf16(qa[m], sb[n],  accz[m][n], 0, 0, 0);
                    S_acc[m][n] = __builtin_amdgcn_mfma_f32_16x16x32_bf16(va[m], kb2[n], S_acc[m][n], 0, 0, 0);
                }
        }
        __syncthreads();                          // B4: Ps reads done

        // Y staging
#pragma unroll
        for (int m = 0; m < 2; ++m)
#pragma unroll
            for (int n = 0; n < 2; ++n)
#pragma unroll
                for (int j = 0; j < 4; ++j) {
                    int t = wr * 32 + m * 16 + lk * 4 + j;
                    int d = wc * 32 + n * 16 + lr;
                    float ge = exp2f((float)(t + 1) * l2g);
                    Ps[swz(t, d)] = f2bf(accy[m][n][j] + ge * accz[m][n][j]);
                }
        __syncthreads();                          // B5

        // coalesced Y write
#pragma unroll
        for (int i = 0; i < 2; ++i) {
            int f  = tid + i * 256;
            int rr = f >> 3;
            int ch = f & 7;
            bf16x8 val = *(const bf16x8*)&Ps[swz(rr, ch * 8)];
            unsigned short* p = Y + ((size_t)(b * NL + c * CK + rr)) * ND + h * DKH + ch * 8;
            *(bf16x8*)p = val;
        }
    }
}

extern "C" void kernel_launch(void* const* d_in, const int* in_sizes, int n_in,
                              void* d_out, int out_size, void* d_ws, size_t ws_size,
                              hipStream_t stream)
{
    (void)in_sizes; (void)n_in; (void)out_size; (void)ws_size;
    const float* x  = (const float*)d_in[0];
    const float* Wq = (const float*)d_in[1];
    const float* Wo = (const float*)d_in[2];
    const float* lg = (const float*)d_in[3];
    float* out = (float*)d_out;

    const size_t SZ  = (size_t)NB * NH * NL * DKH;             // 8M
    const size_t GSZ = (size_t)NB * NH * NG * DKH * DKH;       // 2M
    unsigned short* xb  = (unsigned short*)d_ws;
    unsigned short* Wqb = xb + SZ;
    unsigned short* Wob = Wqb + (size_t)3 * ND * ND;
    unsigned short* Qb  = Wob + (size_t)ND * ND;
    unsigned short* Kb  = Qb + SZ;
    unsigned short* Vb  = Kb + SZ;
    unsigned short* GL  = Vb + SZ;
    unsigned short* GS  = GL + GSZ;
    unsigned short* Ybb = GS + GSZ;

    k_cast_all<<<2048, 256, 0, stream>>>(x, Wq, Wo, xb, Wqb, Wob);
    k_gemm_qkv_bf16<<<dim3(3 * ND / 128, NM / 128), 256, 0, stream>>>(xb, Wqb, Qb, Kb, Vb);
    k_group_state<<<dim3(NB * NH * NG), 256, 0, stream>>>(Kb, Vb, lg, GL);
    k_scan16<<<dim3(NB * NH, 16), 64, 0, stream>>>(GL, lg, GS);
    k_chunk_out4<<<dim3(NB * NH * NG), 256, 0, stream>>>(Qb, Kb, Vb, GS, lg, Ybb);
    k_gemm_out_bf16<<<dim3(ND / 128, NM / 128), 256, 0, stream>>>(Ybb, Wob, out);
}

// Round 11
// 135.254 us; speedup vs baseline: 1.0053x; 1.0053x over previous
//
#include <hip/hip_runtime.h>
#include <cstddef>

// RetNetAttention round 11: exact revert to R7 (best proven: 135.27us, absmax 0.125).
// R10's 256x128 dbuf out-GEMM showed nondeterministic post-timing divergence -> dropped.
#define NB 2
#define NL 4096
#define ND 1024
#define NH 16
#define DKH 64
#define CK 64
#define NCH (NL / CK)
#define NM (NB * NL)
#define KD 1024

typedef __attribute__((ext_vector_type(8))) short bf16x8;
typedef __attribute__((ext_vector_type(4))) float f32x4;

__device__ __forceinline__ float dsigmoid(float x) { return 1.0f / (1.0f + __expf(-x)); }
__device__ __forceinline__ float bf2f(unsigned short u) { return __uint_as_float((unsigned)u << 16); }
__device__ __forceinline__ unsigned short f2bf(float f) {
    unsigned u = __float_as_uint(f);
    u = (u + 0x7fffu + ((u >> 16) & 1u)) >> 16;
    return (unsigned short)u;
}
// element index into [R][64]-ushort tile, XOR-swizzled at 8-elem (16B) granularity
__device__ __forceinline__ int swz(int row, int col) { return row * 64 + (col ^ ((row & 7) << 3)); }

__device__ __forceinline__ void gload16(const void* g, void* l) {
    __builtin_amdgcn_global_load_lds(
        (const __attribute__((address_space(1))) unsigned int*)g,
        (__attribute__((address_space(3))) unsigned int*)l, 16, 0, 0);
}

// ================= fused fp32 -> bf16 casts =================
__global__ __launch_bounds__(256)
void k_cast_all(const float* __restrict__ x, const float* __restrict__ Wq,
                const float* __restrict__ Wo, unsigned short* __restrict__ xb,
                unsigned short* __restrict__ Wqb, unsigned short* __restrict__ Wob)
{
    const int N1 = NB * NL * ND / 4;
    const int N2 = 3 * ND * ND / 4;
    const int N3 = ND * ND / 4;
    const int total = N1 + N2 + N3;
    int i = blockIdx.x * 256 + threadIdx.x;
    const int stride = gridDim.x * 256;
    for (; i < total; i += stride) {
        const float4* src;
        ushort4* dst;
        int j;
        if (i < N1)            { src = (const float4*)x;  dst = (ushort4*)xb;  j = i; }
        else if (i < N1 + N2)  { src = (const float4*)Wq; dst = (ushort4*)Wqb; j = i - N1; }
        else                   { src = (const float4*)Wo; dst = (ushort4*)Wob; j = i - N1 - N2; }
        float4 v = src[j];
        ushort4 o;
        o.x = f2bf(v.x); o.y = f2bf(v.y); o.z = f2bf(v.z); o.w = f2bf(v.w);
        dst[j] = o;
    }
}

// ====== bf16 MFMA GEMM (NT), 128x128 tile, BK=64, swizzled LDS reads (proven 899 TF) ======
__global__ __launch_bounds__(256)
void k_gemm_qkv_bf16(const unsigned short* __restrict__ A, const unsigned short* __restrict__ Bm,
                     unsigned short* __restrict__ Qb, unsigned short* __restrict__ Kb,
                     unsigned short* __restrict__ Vb)
{
    __shared__ short As[128 * 64];
    __shared__ short Bs[128 * 64];
    const int tid = threadIdx.x;
    const int w = tid >> 6, lane = tid & 63;
    const int wr = w >> 1, wc = w & 1;
    const int lr = lane & 15, lk = lane >> 4;

    // T1 bijective XCD swizzle (nwg % 8 == 0)
    const int nbx = gridDim.x;
    const int nwg = nbx * gridDim.y;
    const int bid = blockIdx.y * nbx + blockIdx.x;
    const int sb  = (bid & 7) * (nwg >> 3) + (bid >> 3);
    const int row0 = (sb / nbx) * 128, col0 = (sb % nbx) * 128;

    const int srow = tid >> 3;                         // 0..31
    const int schk = (tid & 7) ^ (srow & 7);           // pre-swizzled source chunk
    const unsigned short* gA = A + (size_t)(row0 + srow) * KD + schk * 8;
    const unsigned short* gB = Bm + (size_t)(col0 + srow) * KD + schk * 8;
    short* lA = As + (w * 8) * 64;
    short* lB = Bs + (w * 8) * 64;

    f32x4 acc[4][4];
#pragma unroll
    for (int m = 0; m < 4; ++m)
#pragma unroll
        for (int n = 0; n < 4; ++n) acc[m][n] = (f32x4){0.f, 0.f, 0.f, 0.f};

    int arow[4], brow[4];
#pragma unroll
    for (int m = 0; m < 4; ++m) arow[m] = (wr * 64 + m * 16 + lr) * 64;
#pragma unroll
    for (int n = 0; n < 4; ++n) brow[n] = (wc * 64 + n * 16 + lr) * 64;
    const int xr = lr & 7;
    const int coff0 = ((0 * 4 + lk) ^ xr) * 8;
    const int coff1 = ((1 * 4 + lk) ^ xr) * 8;

    for (int k0 = 0; k0 < KD; k0 += 64) {
#pragma unroll
        for (int i = 0; i < 4; ++i) gload16(gA + (size_t)(i * 32) * KD + k0, lA + i * 2048);
#pragma unroll
        for (int i = 0; i < 4; ++i) gload16(gB + (size_t)(i * 32) * KD + k0, lB + i * 2048);
        __syncthreads();
#pragma unroll
        for (int kk = 0; kk < 2; ++kk) {
            const int co = kk ? coff1 : coff0;
            bf16x8 a[4], b[4];
#pragma unroll
            for (int m = 0; m < 4; ++m) a[m] = *(const bf16x8*)(As + arow[m] + co);
#pragma unroll
            for (int n = 0; n < 4; ++n) b[n] = *(const bf16x8*)(Bs + brow[n] + co);
#pragma unroll
            for (int m = 0; m < 4; ++m)
#pragma unroll
                for (int n = 0; n < 4; ++n)
                    acc[m][n] = __builtin_amdgcn_mfma_f32_16x16x32_bf16(a[m], b[n], acc[m][n], 0, 0, 0);
        }
        __syncthreads();
    }

#pragma unroll
    for (int m = 0; m < 4; ++m) {
        const int mrow0 = row0 + wr * 64 + m * 16 + lk * 4;
#pragma unroll
        for (int n = 0; n < 4; ++n) {
            const int gcol = col0 + wc * 64 + n * 16 + lr;
            const int three = gcol >> 10;
            const int h = (gcol >> 6) & (NH - 1);
            const int d = gcol & (DKH - 1);
            unsigned short* dst = (three == 0) ? Qb : ((three == 1) ? Kb : Vb);
#pragma unroll
            for (int j = 0; j < 4; ++j) {
                const int mr = mrow0 + j;
                const int b = mr >> 12;
                const int t = mr & (NL - 1);
                dst[(((size_t)b * NH + h) * NL + t) * DKH + d] = f2bf(acc[m][n][j]);
            }
        }
    }
}

__global__ __launch_bounds__(256)
void k_gemm_out_bf16(const unsigned short* __restrict__ A, const unsigned short* __restrict__ Bm,
                     float* __restrict__ C)
{
    __shared__ short As[128 * 64];
    __shared__ short Bs[128 * 64];
    const int tid = threadIdx.x;
    const int w = tid >> 6, lane = tid & 63;
    const int wr = w >> 1, wc = w & 1;
    const int lr = lane & 15, lk = lane >> 4;

    const int nbx = gridDim.x;
    const int nwg = nbx * gridDim.y;
    const int bid = blockIdx.y * nbx + blockIdx.x;
    const int sb  = (bid & 7) * (nwg >> 3) + (bid >> 3);
    const int row0 = (sb / nbx) * 128, col0 = (sb % nbx) * 128;

    const int srow = tid >> 3;
    const int schk = (tid & 7) ^ (srow & 7);
    const unsigned short* gA = A + (size_t)(row0 + srow) * KD + schk * 8;
    const unsigned short* gB = Bm + (size_t)(col0 + srow) * KD + schk * 8;
    short* lA = As + (w * 8) * 64;
    short* lB = Bs + (w * 8) * 64;

    f32x4 acc[4][4];
#pragma unroll
    for (int m = 0; m < 4; ++m)
#pragma unroll
        for (int n = 0; n < 4; ++n) acc[m][n] = (f32x4){0.f, 0.f, 0.f, 0.f};

    int arow[4], brow[4];
#pragma unroll
    for (int m = 0; m < 4; ++m) arow[m] = (wr * 64 + m * 16 + lr) * 64;
#pragma unroll
    for (int n = 0; n < 4; ++n) brow[n] = (wc * 64 + n * 16 + lr) * 64;
    const int xr = lr & 7;
    const int coff0 = ((0 * 4 + lk) ^ xr) * 8;
    const int coff1 = ((1 * 4 + lk) ^ xr) * 8;

    for (int k0 = 0; k0 < KD; k0 += 64) {
#pragma unroll
        for (int i = 0; i < 4; ++i) gload16(gA + (size_t)(i * 32) * KD + k0, lA + i * 2048);
#pragma unroll
        for (int i = 0; i < 4; ++i) gload16(gB + (size_t)(i * 32) * KD + k0, lB + i * 2048);
        __syncthreads();
#pragma unroll
        for (int kk = 0; kk < 2; ++kk) {
            const int co = kk ? coff1 : coff0;
            bf16x8 a[4], b[4];
#pragma unroll
            for (int m = 0; m < 4; ++m) a[m] = *(const bf16x8*)(As + arow[m] + co);
#pragma unroll
            for (int n = 0; n < 4; ++n) b[n] = *(const bf16x8*)(Bs + brow[n] + co);
#pragma unroll
            for (int m = 0; m < 4; ++m)
#pragma unroll
                for (int n = 0; n < 4; ++n)
                    acc[m][n] = __builtin_amdgcn_mfma_f32_16x16x32_bf16(a[m], b[n], acc[m][n], 0, 0, 0);
        }
        __syncthreads();
    }

#pragma unroll
    for (int m = 0; m < 4; ++m) {
        const int mrow0 = row0 + wr * 64 + m * 16 + lk * 4;
#pragma unroll
        for (int n = 0; n < 4; ++n) {
            const int gcol = col0 + wc * 64 + n * 16 + lr;
#pragma unroll
            for (int j = 0; j < 4; ++j)
                C[(size_t)(mrow0 + j) * ND + gcol] = acc[m][n][j];
        }
    }
}

// ====== per-chunk local state (LN fused): SL[d][e] = sum_s g^{63-s} v_s[d] ln(k_s)[e] ======
__global__ __launch_bounds__(256)
void k_chunk_state(const unsigned short* __restrict__ Kb, const unsigned short* __restrict__ Vb,
                   const float* __restrict__ lg, unsigned short* __restrict__ SL)
{
    __shared__ unsigned short Kt[64 * 64];
    __shared__ unsigned short Vt[64 * 64];
    __shared__ float red[64][8];
    const int blk = blockIdx.x;
    const int c   = blk & (NCH - 1);
    const int bh  = blk >> 6;
    const int h   = bh & (NH - 1);
    const float gamma = dsigmoid(lg[h]);
    const float l2g = log2f(gamma);
    const int tid = threadIdx.x;
    const unsigned short* Kc = Kb + ((size_t)bh * NL + c * CK) * DKH;
    const unsigned short* Vc = Vb + ((size_t)bh * NL + c * CK) * DKH;

    const int r  = tid & 63;
    const int w4 = tid >> 6;
    const int c0 = w4 * 8;
    bf16x8 k8a = *(const bf16x8*)(Kc + (size_t)r * DKH + c0);
    bf16x8 k8b = *(const bf16x8*)(Kc + (size_t)r * DKH + c0 + 32);
    bf16x8 v8a = *(const bf16x8*)(Vc + (size_t)r * DKH + c0);
    bf16x8 v8b = *(const bf16x8*)(Vc + (size_t)r * DKH + c0 + 32);
    float sum = 0.f, sq = 0.f;
#pragma unroll
    for (int j = 0; j < 8; ++j) {
        float xa = bf2f((unsigned short)k8a[j]); sum += xa; sq += xa * xa;
        float xb = bf2f((unsigned short)k8b[j]); sum += xb; sq += xb * xb;
    }
    red[r][w4] = sum; red[r][w4 + 4] = sq;
    __syncthreads();
    float s  = red[r][0] + red[r][1] + red[r][2] + red[r][3];
    float qq = red[r][4] + red[r][5] + red[r][6] + red[r][7];
    float mu = s * (1.0f / 64.0f);
    float rstd = rsqrtf(qq * (1.0f / 64.0f) - mu * mu + 1e-5f);
    float wgt = exp2f((float)(CK - 1 - r) * l2g);
#pragma unroll
    for (int j = 0; j < 8; ++j) {
        Kt[swz(c0 + j, r)]      = f2bf((bf2f((unsigned short)k8a[j]) - mu) * rstd);
        Kt[swz(c0 + 32 + j, r)] = f2bf((bf2f((unsigned short)k8b[j]) - mu) * rstd);
        Vt[swz(c0 + j, r)]      = f2bf(bf2f((unsigned short)v8a[j]) * wgt);
        Vt[swz(c0 + 32 + j, r)] = f2bf(bf2f((unsigned short)v8b[j]) * wgt);
    }
    __syncthreads();

    const int w = tid >> 6, lane = tid & 63;
    const int wr = w >> 1, wc = w & 1;
    const int lr = lane & 15, lk = lane >> 4;
    f32x4 acc[2][2];
#pragma unroll
    for (int m = 0; m < 2; ++m)
#pragma unroll
        for (int n = 0; n < 2; ++n) acc[m][n] = (f32x4){0.f, 0.f, 0.f, 0.f};
#pragma unroll
    for (int kk = 0; kk < 2; ++kk) {
        const int so = kk * 32 + lk * 8;
        bf16x8 a[2], b[2];
#pragma unroll
        for (int m = 0; m < 2; ++m) a[m] = *(const bf16x8*)&Vt[swz(wr * 32 + m * 16 + lr, so)];
#pragma unroll
        for (int n = 0; n < 2; ++n) b[n] = *(const bf16x8*)&Kt[swz(wc * 32 + n * 16 + lr, so)];
#pragma unroll
        for (int m = 0; m < 2; ++m)
#pragma unroll
            for (int n = 0; n < 2; ++n)
                acc[m][n] = __builtin_amdgcn_mfma_f32_16x16x32_bf16(a[m], b[n], acc[m][n], 0, 0, 0);
    }

    unsigned short* out = SL + (size_t)blk * (DKH * DKH);
#pragma unroll
    for (int m = 0; m < 2; ++m)
#pragma unroll
        for (int n = 0; n < 2; ++n)
#pragma unroll
            for (int j = 0; j < 4; ++j) {
                int d = wr * 32 + m * 16 + lk * 4 + j;
                int e = wc * 32 + n * 16 + lr;
                out[d * DKH + e] = f2bf(acc[m][n][j]);
            }
}

// ====== sequential scan over chunks: SS[c] = state BEFORE chunk c ======
// 512 one-wave blocks (32 bh x 16 slices of the 64x64 state) for full-chip occupancy.
__global__ __launch_bounds__(64)
void k_scan(const unsigned short* __restrict__ SL, const float* __restrict__ lg,
            unsigned short* __restrict__ SS)
{
    const int bh = blockIdx.x;
    const int qt = blockIdx.y;                 // 0..15
    const int h  = bh & (NH - 1);
    const float gamma = dsigmoid(lg[h]);
    const float dc = __powf(gamma, (float)CK);
    const size_t base = (size_t)bh * NCH * (DKH * DKH) + qt * 256 + threadIdx.x * 4;
    float s0 = 0.f, s1 = 0.f, s2 = 0.f, s3 = 0.f;
    for (int c = 0; c < NCH; ++c) {
        const size_t off = base + (size_t)c * (DKH * DKH);
        ushort4 l = *(const ushort4*)(SL + off);
        ushort4 o;
        o.x = f2bf(s0); o.y = f2bf(s1); o.z = f2bf(s2); o.w = f2bf(s3);
        *(ushort4*)(SS + off) = o;
        s0 = s0 * dc + bf2f(l.x); s1 = s1 * dc + bf2f(l.y);
        s2 = s2 * dc + bf2f(l.z); s3 = s3 * dc + bf2f(l.w);
    }
}

// ====== per-chunk output (LN fused): Y = mask(Q K^T)V + g^{t+1} Q S^T, coalesced bf16 out ======
__global__ __launch_bounds__(256)
void k_chunk_out(const unsigned short* __restrict__ Qb, const unsigned short* __restrict__ Kb,
                 const unsigned short* __restrict__ Vb, const unsigned short* __restrict__ SS,
                 const float* __restrict__ lg, unsigned short* __restrict__ Y)
{
    __shared__ unsigned short Qs[64 * 64];
    __shared__ unsigned short Ks[64 * 64];
    __shared__ unsigned short Vt[64 * 64];
    __shared__ unsigned short Ss[64 * 64];
    __shared__ unsigned short Ps[64 * 64];   // reused as Y-staging
    __shared__ float red[64][8];
    const int blk = blockIdx.x;
    const int c   = blk & (NCH - 1);
    const int bh  = blk >> 6;
    const int h   = bh & (NH - 1);
    const int b   = bh >> 4;
    const float gamma = dsigmoid(lg[h]);
    const float l2g = log2f(gamma);
    const int tid = threadIdx.x;
    const unsigned short* Qc = Qb + ((size_t)bh * NL + c * CK) * DKH;
    const unsigned short* Kc = Kb + ((size_t)bh * NL + c * CK) * DKH;
    const unsigned short* Vc = Vb + ((size_t)bh * NL + c * CK) * DKH;
    const unsigned short* Sc = SS + (size_t)blk * (DKH * DKH);

    const int r  = tid & 63;
    const int w4 = tid >> 6;
    const int c0 = w4 * 8;
    bf16x8 q8a = *(const bf16x8*)(Qc + (size_t)r * DKH + c0);
    bf16x8 q8b = *(const bf16x8*)(Qc + (size_t)r * DKH + c0 + 32);
    bf16x8 k8a = *(const bf16x8*)(Kc + (size_t)r * DKH + c0);
    bf16x8 k8b = *(const bf16x8*)(Kc + (size_t)r * DKH + c0 + 32);
    bf16x8 v8a = *(const bf16x8*)(Vc + (size_t)r * DKH + c0);
    bf16x8 v8b = *(const bf16x8*)(Vc + (size_t)r * DKH + c0 + 32);
    bf16x8 s8a = *(const bf16x8*)(Sc + (size_t)r * DKH + c0);
    bf16x8 s8b = *(const bf16x8*)(Sc + (size_t)r * DKH + c0 + 32);
    float sum = 0.f, sq = 0.f;
#pragma unroll
    for (int j = 0; j < 8; ++j) {
        float xa = bf2f((unsigned short)k8a[j]); sum += xa; sq += xa * xa;
        float xb = bf2f((unsigned short)k8b[j]); sum += xb; sq += xb * xb;
    }
    red[r][w4] = sum; red[r][w4 + 4] = sq;
    __syncthreads();
    float sm = red[r][0] + red[r][1] + red[r][2] + red[r][3];
    float qq = red[r][4] + red[r][5] + red[r][6] + red[r][7];
    float mu = sm * (1.0f / 64.0f);
    float rstd = rsqrtf(qq * (1.0f / 64.0f) - mu * mu + 1e-5f);
    *(bf16x8*)&Qs[swz(r, c0)]      = q8a;
    *(bf16x8*)&Qs[swz(r, c0 + 32)] = q8b;
    *(bf16x8*)&Ss[swz(r, c0)]      = s8a;
    *(bf16x8*)&Ss[swz(r, c0 + 32)] = s8b;
#pragma unroll
    for (int j = 0; j < 8; ++j) {
        Ks[swz(r, c0 + j)]      = f2bf((bf2f((unsigned short)k8a[j]) - mu) * rstd);
        Ks[swz(r, c0 + 32 + j)] = f2bf((bf2f((unsigned short)k8b[j]) - mu) * rstd);
        Vt[swz(c0 + j, r)]      = (unsigned short)v8a[j];
        Vt[swz(c0 + 32 + j, r)] = (unsigned short)v8b[j];
    }
    __syncthreads();

    const int w = tid >> 6, lane = tid & 63;
    const int wr = w >> 1, wc = w & 1;
    const int lr = lane & 15, lk = lane >> 4;

    // phase A: P = Q K^T with causal decay
    f32x4 accp[2][2];
#pragma unroll
    for (int m = 0; m < 2; ++m)
#pragma unroll
        for (int n = 0; n < 2; ++n) accp[m][n] = (f32x4){0.f, 0.f, 0.f, 0.f};
#pragma unroll
    for (int kk = 0; kk < 2; ++kk) {
        const int eo = kk * 32 + lk * 8;
        bf16x8 a[2], bfr[2];
#pragma unroll
        for (int m = 0; m < 2; ++m) a[m]   = *(const bf16x8*)&Qs[swz(wr * 32 + m * 16 + lr, eo)];
#pragma unroll
        for (int n = 0; n < 2; ++n) bfr[n] = *(const bf16x8*)&Ks[swz(wc * 32 + n * 16 + lr, eo)];
#pragma unroll
        for (int m = 0; m < 2; ++m)
#pragma unroll
            for (int n = 0; n < 2; ++n)
                accp[m][n] = __builtin_amdgcn_mfma_f32_16x16x32_bf16(a[m], bfr[n], accp[m][n], 0, 0, 0);
    }
#pragma unroll
    for (int m = 0; m < 2; ++m)
#pragma unroll
        for (int n = 0; n < 2; ++n)
#pragma unroll
            for (int j = 0; j < 4; ++j) {
                int t = wr * 32 + m * 16 + lk * 4 + j;
                int s = wc * 32 + n * 16 + lr;
                int dt = t - s;
                float v = (dt >= 0) ? accp[m][n][j] * exp2f((float)dt * l2g) : 0.0f;
                Ps[swz(t, s)] = f2bf(v);
            }
    __syncthreads();

    // phase B
    f32x4 accy[2][2], accz[2][2];
#pragma unroll
    for (int m = 0; m < 2; ++m)
#pragma unroll
        for (int n = 0; n < 2; ++n) {
            accy[m][n] = (f32x4){0.f, 0.f, 0.f, 0.f};
            accz[m][n] = (f32x4){0.f, 0.f, 0.f, 0.f};
        }
#pragma unroll
    for (int kk = 0; kk < 2; ++kk) {
        const int so = kk * 32 + lk * 8;
        bf16x8 pa[2], qa[2], vb[2], sb[2];
#pragma unroll
        for (int m = 0; m < 2; ++m) {
            pa[m] = *(const bf16x8*)&Ps[swz(wr * 32 + m * 16 + lr, so)];
            qa[m] = *(const bf16x8*)&Qs[swz(wr * 32 + m * 16 + lr, so)];
        }
#pragma unroll
        for (int n = 0; n < 2; ++n) {
            vb[n] = *(const bf16x8*)&Vt[swz(wc * 32 + n * 16 + lr, so)];
            sb[n] = *(const bf16x8*)&Ss[swz(wc * 32 + n * 16 + lr, so)];
        }
#pragma unroll
        for (int m = 0; m < 2; ++m)
#pragma unroll
            for (int n = 0; n < 2; ++n) {
                accy[m][n] = __builtin_amdgcn_mfma_f32_16x16x32_bf16(pa[m], vb[n], accy[m][n], 0, 0, 0);
                accz[m][n] = __builtin_amdgcn_mfma_f32_16x16x32_bf16(qa[m], sb[n], accz[m][n], 0, 0, 0);
            }
    }
    __syncthreads();   // Ps reads done; safe to overwrite as Y-staging

#pragma unroll
    for (int m = 0; m < 2; ++m)
#pragma unroll
        for (int n = 0; n < 2; ++n)
#pragma unroll
            for (int j = 0; j < 4; ++j) {
                int t = wr * 32 + m * 16 + lk * 4 + j;
                int d = wc * 32 + n * 16 + lr;
                float g = exp2f((float)(t + 1) * l2g);
                Ps[swz(t, d)] = f2bf(accy[m][n][j] + g * accz[m][n][j]);
            }
    __syncthreads();

    // coalesced write: each row = 128B contiguous
#pragma unroll
    for (int i = 0; i < 2; ++i) {
        int f  = tid + i * 256;
        int rr = f >> 3;
        int ch = f & 7;
        bf16x8 val = *(const bf16x8*)&Ps[swz(rr, ch * 8)];
        unsigned short* p = Y + ((size_t)(b * NL + c * CK + rr)) * ND + h * DKH + ch * 8;
        *(bf16x8*)p = val;
    }
}

extern "C" void kernel_launch(void* const* d_in, const int* in_sizes, int n_in,
                              void* d_out, int out_size, void* d_ws, size_t ws_size,
                              hipStream_t stream)
{
    (void)in_sizes; (void)n_in; (void)out_size; (void)ws_size;
    const float* x  = (const float*)d_in[0];
    const float* Wq = (const float*)d_in[1];
    const float* Wo = (const float*)d_in[2];
    const float* lg = (const float*)d_in[3];
    float* out = (float*)d_out;

    const size_t SZ = (size_t)NB * NH * NL * DKH;
    unsigned short* xb  = (unsigned short*)d_ws;
    unsigned short* Wqb = xb + SZ;
    unsigned short* Wob = Wqb + (size_t)3 * ND * ND;
    unsigned short* Qb  = Wob + (size_t)ND * ND;
    unsigned short* Kb  = Qb + SZ;
    unsigned short* Vb  = Kb + SZ;
    unsigned short* SL  = Vb + SZ;
    unsigned short* SS  = SL + SZ;
    unsigned short* Ybb = SS + SZ;

    k_cast_all<<<2048, 256, 0, stream>>>(x, Wq, Wo, xb, Wqb, Wob);
    k_gemm_qkv_bf16<<<dim3(3 * ND / 128, NM / 128), 256, 0, stream>>>(xb, Wqb, Qb, Kb, Vb);
    k_chunk_state<<<dim3(NB * NH * NCH), 256, 0, stream>>>(Kb, Vb, lg, SL);
    k_scan<<<dim3(NB * NH, 16), 64, 0, stream>>>(SL, lg, SS);
    k_chunk_out<<<dim3(NB * NH * NCH), 256, 0, stream>>>(Qb, Kb, Vb, SS, lg, Ybb);
    k_gemm_out_bf16<<<dim3(ND / 128, NM / 128), 256, 0, stream>>>(Ybb, Wob, out);
}